// Round 4
// baseline (239.852 us; speedup 1.0000x reference)
//
#include <hip/hip_runtime.h>
#include <hip/hip_bf16.h>
#include <hip/hip_fp16.h>

#define IN_F   4096
#define OUT_F  8192
#define M_ROWS 256
#define SLAB   256                 // k-elements per LDS slab
#define NSLAB  (IN_F / SLAB)       // 16

typedef __attribute__((ext_vector_type(8))) short  short8;   // 8 bf16
typedef __attribute__((ext_vector_type(4))) float  float4v;  // 4 fp32 acc

union BF8 { uint4 u; short8 s; };

// pack two fp32 into bf16x2 (truncation)
__device__ inline unsigned int pack_bf16(float lo, float hi) {
    return __builtin_amdgcn_perm(__float_as_uint(hi), __float_as_uint(lo), 0x07060302u);
}

// x fp32 -> bf16 (truncated) into workspace
__global__ void cvt_x_kernel(const float* __restrict__ x, unsigned short* __restrict__ xb) {
    int i = blockIdx.x * blockDim.x + threadIdx.x;   // one float4 per thread
    if (i < (M_ROWS * IN_F) / 4) {
        float4 v = ((const float4*)x)[i];
        uint2 o;
        o.x = pack_bf16(v.x, v.y);
        o.y = pack_bf16(v.z, v.w);
        ((uint2*)xb)[i] = o;
    }
}

// C[256,8192] = X * W^T + bias, fused 2-bit dequant of W.
// Block: 64m x 64n, 4 waves; each wave owns 64m x 16n.
// A (x, bf16) double-buffered in LDS, K in 16 slabs of 256 -> 16 barriers total.
// B dequanted per-lane directly into MFMA fragments (no LDS, no barrier).
template <bool XB>
__global__ __launch_bounds__(256, 2) void gemm2bit_kernel(
    const float*           __restrict__ xf,     // used when !XB
    const unsigned short*  __restrict__ xb,     // used when XB (bf16 x in ws)
    const int*             __restrict__ wq,     // int i holds weights 4i..4i+3 in bits 0,2,4,6
    const void*            __restrict__ wnorm,  // per-group-of-16 norm; fp32 or fp16, detected
    const float*           __restrict__ bias,
    float*                 __restrict__ out)
{
    // A tile: 64 rows x 256 k (bf16), XOR-swizzled 8-short chunks, x2 buffers = 64 KB
    __shared__ unsigned short ldsA[2][64 * SLAB];

    const int t    = threadIdx.x;
    const int n0   = blockIdx.x * 64;
    const int m0   = blockIdx.y * 64;
    const int wave = t >> 6;
    const int lane = t & 63;
    const int l15  = lane & 15;
    const int quad = lane >> 4;

    // norm storage detection (valid norms in [1e-4, 0.0501]); grid-uniform.
    const float cand0 = *(const float*)wnorm;
    const bool  nf32  = (cand0 > 1e-5f && cand0 < 0.1f);
    const float*  nF = (const float*)wnorm;
    const __half* nH = (const __half*)wnorm;

    // this wave's output column / weight row
    const int   ncol = n0 + wave * 16 + l15;
    const float bv   = bias[ncol];

    // B addressing: per global k-step ksg (K=32 each):
    //   packed ints:  wq + ncol*1024 + ksg*8 + quad*2   (int2 -> 8 weights)
    //   norm index :  ncol*256 + ksg*2 + (quad>>1)
    const int* wqBase  = wq + ncol * (IN_F / 4) + quad * 2;
    const int  nrmBase = ncol * (IN_F / 16) + (quad >> 1);

    // A staging: thread -> (row = t&63, k-group = (t>>6)*64 shorts, 8 x uint4)
    const int srow = t & 63;
    const int skq  = t >> 6;
    const int sr7  = srow & 7;
    const int wbase = srow * SLAB + skq * 64;

    // A fragment LDS offsets (shorts), swizzle: chunk_low = ((ks&1)*4+quad) ^ (l15&7)
    int fe[4], fo[4];
#pragma unroll
    for (int i = 0; i < 4; ++i) {
        const int row = i * 16 + l15;
        fe[i] = row * SLAB + ((quad     ) ^ (l15 & 7)) * 8;
        fo[i] = row * SLAB + ((quad ^ 4 ) ^ (l15 & 7)) * 8;  // (4+quad)^x == (quad^4)^x
    }

    float4v acc[4] = {};

    // ---- prologue: stage slab 0 ----
    uint4 stg[8];
    if (XB) {
        const uint4* g = (const uint4*)(xb + (m0 + srow) * IN_F + skq * 64);
#pragma unroll
        for (int i = 0; i < 8; ++i) stg[i] = g[i];
    } else {
        const float4* g = (const float4*)(xf + (m0 + srow) * IN_F + skq * 64);
#pragma unroll
        for (int i = 0; i < 8; ++i) {
            float4 v0 = g[2 * i], v1 = g[2 * i + 1];
            stg[i].x = pack_bf16(v0.x, v0.y); stg[i].y = pack_bf16(v0.z, v0.w);
            stg[i].z = pack_bf16(v1.x, v1.y); stg[i].w = pack_bf16(v1.z, v1.w);
        }
    }
    {
        unsigned short* B = ldsA[0];
#pragma unroll
        for (int i = 0; i < 8; ++i)
            *(uint4*)&B[wbase + ((i ^ sr7) << 3)] = stg[i];
    }

    for (int s = 0; s < NSLAB; ++s) {
        __syncthreads();   // slab s staged; all waves done with buffer s&1 from slab s-2

        // ---- issue next-slab global loads early (hidden by compute below) ----
        uint4 nxt[8];
        if (s + 1 < NSLAB) {
            if (XB) {
                const uint4* g = (const uint4*)(xb + (m0 + srow) * IN_F + (s + 1) * SLAB + skq * 64);
#pragma unroll
                for (int i = 0; i < 8; ++i) nxt[i] = g[i];
            } else {
                const float4* g = (const float4*)(xf + (m0 + srow) * IN_F + (s + 1) * SLAB + skq * 64);
#pragma unroll
                for (int i = 0; i < 8; ++i) {
                    float4 v0 = g[2 * i], v1 = g[2 * i + 1];
                    nxt[i].x = pack_bf16(v0.x, v0.y); nxt[i].y = pack_bf16(v0.z, v0.w);
                    nxt[i].z = pack_bf16(v1.x, v1.y); nxt[i].w = pack_bf16(v1.z, v1.w);
                }
            }
        }

        // ---- compute: 8 k-steps from buffer s&1, no barriers ----
        const unsigned short* A  = ldsA[s & 1];
        const int*  wqS  = wqBase  + s * 64;   // + ks*8 ints
        const int   nrmS = nrmBase + s * 16;   // + ks*2

#pragma unroll
        for (int ks = 0; ks < 8; ++ks) {
            // B fragment: 8 weights for (row=ncol, k = s*256 + ks*32 + quad*8 + j)
            const int2  q  = *(const int2*)(wqS + ks * 8);
            const int   gi = nrmS + ks * 2;
            const float nn = nf32 ? nF[gi] : __half2float(nH[gi]);
            const float sc = nn * (2.0f / 3.0f);

            float f0 = fmaf((float)((q.x      ) & 3), sc, -nn);
            float f1 = fmaf((float)((q.x >>  2) & 3), sc, -nn);
            float f2 = fmaf((float)((q.x >>  4) & 3), sc, -nn);
            float f3 = fmaf((float)((q.x >>  6) & 3), sc, -nn);
            float f4 = fmaf((float)((q.y      ) & 3), sc, -nn);
            float f5 = fmaf((float)((q.y >>  2) & 3), sc, -nn);
            float f6 = fmaf((float)((q.y >>  4) & 3), sc, -nn);
            float f7 = fmaf((float)((q.y >>  6) & 3), sc, -nn);

            BF8 bb;
            bb.u.x = pack_bf16(f0, f1);
            bb.u.y = pack_bf16(f2, f3);
            bb.u.z = pack_bf16(f4, f5);
            bb.u.w = pack_bf16(f6, f7);

            const int ko = (ks >> 1) * 64;   // shorts
#pragma unroll
            for (int i = 0; i < 4; ++i) {
                const int off = ((ks & 1) ? fo[i] : fe[i]) + ko;
                short8 a = *(const short8*)&A[off];
                acc[i] = __builtin_amdgcn_mfma_f32_16x16x32_bf16(a, bb.s, acc[i], 0, 0, 0);
            }
        }

        // ---- stage next slab into the other buffer (no barrier needed here) ----
        if (s + 1 < NSLAB) {
            unsigned short* B = ldsA[(s + 1) & 1];
#pragma unroll
            for (int i = 0; i < 8; ++i)
                *(uint4*)&B[wbase + ((i ^ sr7) << 3)] = nxt[i];
        }
    }

    // ---- epilogue: D[row = m0 + i*16 + quad*4 + r][col = ncol] ----
#pragma unroll
    for (int i = 0; i < 4; ++i) {
        const int row0 = m0 + i * 16 + quad * 4;
#pragma unroll
        for (int r = 0; r < 4; ++r) {
            out[(row0 + r) * OUT_F + ncol] = acc[i][r] + bv;
        }
    }
}

extern "C" void kernel_launch(void* const* d_in, const int* in_sizes, int n_in,
                              void* d_out, int out_size, void* d_ws, size_t ws_size,
                              hipStream_t stream) {
    const float* x    = (const float*)d_in[0];
    const int*   wq   = (const int*)d_in[1];
    const void*  wn   = (const void*)d_in[2];
    const float* bias = (const float*)d_in[3];
    float*       out  = (float*)d_out;

    const bool use_ws = ws_size >= (size_t)(M_ROWS * IN_F * sizeof(unsigned short));

    dim3 grid(OUT_F / 64, M_ROWS / 64);  // 128 x 4 = 512 blocks (2 per CU)

    if (use_ws) {
        unsigned short* xb = (unsigned short*)d_ws;
        cvt_x_kernel<<<dim3((M_ROWS * IN_F / 4 + 255) / 256), 256, 0, stream>>>(x, xb);
        gemm2bit_kernel<true><<<grid, 256, 0, stream>>>(nullptr, xb, wq, wn, bias, out);
    } else {
        gemm2bit_kernel<false><<<grid, 256, 0, stream>>>(x, nullptr, wq, wn, bias, out);
    }
}

// Round 5
// 154.729 us; speedup vs baseline: 1.5501x; 1.5501x over previous
//
#include <hip/hip_runtime.h>
#include <hip/hip_bf16.h>
#include <hip/hip_fp16.h>

#define IN_F   4096
#define OUT_F  8192
#define M_ROWS 256
#define SLAB   256                 // k-elements per LDS slab
#define NSLAB  (IN_F / SLAB)       // 16

typedef __attribute__((ext_vector_type(8))) short  short8;   // 8 bf16
typedef __attribute__((ext_vector_type(4))) float  float4v;  // 4 fp32 acc

union BF8 { uint4 u; short8 s; };

typedef __attribute__((address_space(1))) const unsigned int glb_uint;
typedef __attribute__((address_space(3))) unsigned int       lds_uint;

__device__ inline void gld_lds16(const void* g, void* l) {
    __builtin_amdgcn_global_load_lds((glb_uint*)g, (lds_uint*)l, 16, 0, 0);
}

// pack two fp32 into bf16x2 (truncation)
__device__ inline unsigned int pack_bf16(float lo, float hi) {
    return __builtin_amdgcn_perm(__float_as_uint(hi), __float_as_uint(lo), 0x07060302u);
}

// x fp32 -> bf16 (truncated) into workspace
__global__ void cvt_x_kernel(const float* __restrict__ x, unsigned short* __restrict__ xb) {
    int i = blockIdx.x * blockDim.x + threadIdx.x;   // one float4 per thread
    if (i < (M_ROWS * IN_F) / 4) {
        float4 v = ((const float4*)x)[i];
        uint2 o;
        o.x = pack_bf16(v.x, v.y);
        o.y = pack_bf16(v.z, v.w);
        ((uint2*)xb)[i] = o;
    }
}

// C[256,8192] = X * W^T + bias, fused 2-bit dequant of W.
// Block 64m x 64n, 4 waves; each wave owns 64m x 16n.
// A: bf16 in LDS, K in 16 slabs of 256, double-buffered, staged via
//    global_load_lds (lane-linear LDS; XOR swizzle applied on the GLOBAL side).
// B: per-lane register dequant directly into MFMA fragments (no LDS).
// One barrier per slab = 16 barriers total, ~32 MFMA per barrier per wave.
template <bool XB>
__global__ __launch_bounds__(256, 2) void gemm2bit_kernel(
    const float*           __restrict__ xf,     // used when !XB
    const unsigned short*  __restrict__ xb,     // used when XB (bf16 x in ws)
    const int*             __restrict__ wq,     // int i holds weights 4i..4i+3 in bits 0,2,4,6
    const void*            __restrict__ wnorm,  // per-group-of-16 norm; fp32 or fp16, detected
    const float*           __restrict__ bias,
    float*                 __restrict__ out)
{
    __shared__ unsigned short ldsA[2][64 * SLAB];   // 2 x 32 KB

    const int t    = threadIdx.x;
    const int n0   = blockIdx.x * 64;
    const int m0   = blockIdx.y * 64;
    const int wave = t >> 6;
    const int lane = t & 63;
    const int l15  = lane & 15;
    const int quad = lane >> 4;

    // norm storage detection (valid norms in [1e-4, 0.0501]); grid-uniform.
    const float cand0 = *(const float*)wnorm;
    const bool  nf32  = (cand0 > 1e-5f && cand0 < 0.1f);
    const float*  nF = (const float*)wnorm;
    const __half* nH = (const __half*)wnorm;

    // this wave's output column / weight row
    const int   ncol = n0 + wave * 16 + l15;
    const float bv   = bias[ncol];
    const int*  wqW  = wq + ncol * (IN_F / 4) + quad * 2;  // + s*64 + ks*8
    const int   nrmW = ncol * (IN_F / 16) + (quad >> 1);   // + s*16 + ks*2

    // staging lane mapping: call c covers rows wave*16 + c*2 + (lane>>5),
    // stored chunk (lane&31); logical chunk = stored ^ (row&7).
    const int srl = lane >> 5;   // 0/1
    const int sj  = lane & 31;   // stored 8-short chunk within row

    // A fragment offsets (shorts): row=(i*16+l15), k-step ks ->
    //   off = row*SLAB + (ks>>1)*64 + (((ks&1)*4+quad)^(l15&7))*8
    const int swzE = ((quad      ) ^ (l15 & 7)) * 8;
    const int swzO = ((quad ^ 4  ) ^ (l15 & 7)) * 8;
    int fb[4];
#pragma unroll
    for (int i = 0; i < 4; ++i) fb[i] = (i * 16 + l15) * SLAB;

    float4v acc[4] = {};

    // ---- staging helper: slab s into buffer b ----
    auto stage = [&](int s, int b) {
        if constexpr (XB) {
#pragma unroll
            for (int c = 0; c < 8; ++c) {
                const int R  = wave * 16 + c * 2 + srl;          // block-local row
                const int lc = sj ^ (R & 7);                     // logical chunk
                const unsigned short* g = xb + (m0 + R) * IN_F + s * SLAB + lc * 8;
                gld_lds16(g, &ldsA[b][(wave * 16 + c * 2) * SLAB]);
            }
        } else {
#pragma unroll
            for (int c = 0; c < 8; ++c) {
                const int R  = wave * 16 + c * 2 + srl;
                const int lc = sj ^ (R & 7);
                const float4* g = (const float4*)(xf + (m0 + R) * IN_F + s * SLAB + lc * 8);
                float4 v0 = g[0], v1 = g[1];
                uint4 o;
                o.x = pack_bf16(v0.x, v0.y); o.y = pack_bf16(v0.z, v0.w);
                o.z = pack_bf16(v1.x, v1.y); o.w = pack_bf16(v1.z, v1.w);
                *(uint4*)&ldsA[b][(wave * 16 + c * 2) * SLAB + lane * 8] = o;
            }
        }
    };

    // ---- prologue ----
    stage(0, 0);

    for (int s = 0; s < NSLAB; ++s) {
        __syncthreads();   // drains vmcnt -> slab s DMA complete; syncs buffers

        if (s + 1 < NSLAB) stage(s + 1, (s + 1) & 1);

        // B packed data for this slab (24 VGPRs, unconditional, fully unrolled)
        int2  qv[8];
        float nv[8];
#pragma unroll
        for (int ks = 0; ks < 8; ++ks) {
            qv[ks] = *(const int2*)(wqW + s * 64 + ks * 8);
            const int gi = nrmW + s * 16 + ks * 2;
            nv[ks] = nf32 ? nF[gi] : __half2float(nH[gi]);
        }

        const unsigned short* A = ldsA[s & 1];
#pragma unroll
        for (int ks = 0; ks < 8; ++ks) {
            const float nn = nv[ks];
            const float sc = nn * (2.0f / 3.0f);
            const int qx = qv[ks].x, qy = qv[ks].y;

            float f0 = fmaf((float)((qx      ) & 3), sc, -nn);
            float f1 = fmaf((float)((qx >>  2) & 3), sc, -nn);
            float f2 = fmaf((float)((qx >>  4) & 3), sc, -nn);
            float f3 = fmaf((float)((qx >>  6) & 3), sc, -nn);
            float f4 = fmaf((float)((qy      ) & 3), sc, -nn);
            float f5 = fmaf((float)((qy >>  2) & 3), sc, -nn);
            float f6 = fmaf((float)((qy >>  4) & 3), sc, -nn);
            float f7 = fmaf((float)((qy >>  6) & 3), sc, -nn);

            BF8 bb;
            bb.u.x = pack_bf16(f0, f1);
            bb.u.y = pack_bf16(f2, f3);
            bb.u.z = pack_bf16(f4, f5);
            bb.u.w = pack_bf16(f6, f7);

            const int ko = (ks >> 1) * 64 + ((ks & 1) ? swzO : swzE);
#pragma unroll
            for (int i = 0; i < 4; ++i) {
                short8 a = *(const short8*)&A[fb[i] + ko];
                acc[i] = __builtin_amdgcn_mfma_f32_16x16x32_bf16(a, bb.s, acc[i], 0, 0, 0);
            }
        }
    }

    // ---- epilogue: D[row = m0 + i*16 + quad*4 + r][col = ncol] ----
#pragma unroll
    for (int i = 0; i < 4; ++i) {
        const int row0 = m0 + i * 16 + quad * 4;
#pragma unroll
        for (int r = 0; r < 4; ++r) {
            out[(row0 + r) * OUT_F + ncol] = acc[i][r] + bv;
        }
    }
}

extern "C" void kernel_launch(void* const* d_in, const int* in_sizes, int n_in,
                              void* d_out, int out_size, void* d_ws, size_t ws_size,
                              hipStream_t stream) {
    const float* x    = (const float*)d_in[0];
    const int*   wq   = (const int*)d_in[1];
    const void*  wn   = (const void*)d_in[2];
    const float* bias = (const float*)d_in[3];
    float*       out  = (float*)d_out;

    const bool use_ws = ws_size >= (size_t)(M_ROWS * IN_F * sizeof(unsigned short));

    dim3 grid(OUT_F / 64, M_ROWS / 64);  // 128 x 4 = 512 blocks (2 per CU)

    if (use_ws) {
        unsigned short* xb = (unsigned short*)d_ws;
        cvt_x_kernel<<<dim3((M_ROWS * IN_F / 4 + 255) / 256), 256, 0, stream>>>(x, xb);
        gemm2bit_kernel<true><<<grid, 256, 0, stream>>>(nullptr, xb, wq, wn, bias, out);
    } else {
        gemm2bit_kernel<false><<<grid, 256, 0, stream>>>(x, nullptr, wq, wn, bias, out);
    }
}

// Round 6
// 154.432 us; speedup vs baseline: 1.5531x; 1.0019x over previous
//
#include <hip/hip_runtime.h>
#include <hip/hip_bf16.h>
#include <hip/hip_fp16.h>

#define IN_F   4096
#define OUT_F  8192
#define M_ROWS 256
#define SLAB   256                 // k-elements per LDS slab
#define NSLAB  (IN_F / SLAB)       // 16

typedef __attribute__((ext_vector_type(8))) short  short8;   // 8 bf16
typedef __attribute__((ext_vector_type(4))) float  float4v;  // 4 fp32 acc

union BF8 { uint4 u; short8 s; };

typedef __attribute__((address_space(1))) const unsigned int glb_uint;
typedef __attribute__((address_space(3))) unsigned int       lds_uint;

__device__ inline void gld_lds16(const void* g, void* l) {
    __builtin_amdgcn_global_load_lds((glb_uint*)g, (lds_uint*)l, 16, 0, 0);
}

// pack two fp32 into bf16x2 (truncation)
__device__ inline unsigned int pack_bf16(float lo, float hi) {
    return __builtin_amdgcn_perm(__float_as_uint(hi), __float_as_uint(lo), 0x07060302u);
}

// x fp32 -> bf16 (truncated) into workspace
__global__ void cvt_x_kernel(const float* __restrict__ x, unsigned short* __restrict__ xb) {
    int i = blockIdx.x * blockDim.x + threadIdx.x;   // one float4 per thread
    if (i < (M_ROWS * IN_F) / 4) {
        float4 v = ((const float4*)x)[i];
        uint2 o;
        o.x = pack_bf16(v.x, v.y);
        o.y = pack_bf16(v.z, v.w);
        ((uint2*)xb)[i] = o;
    }
}

// C[256,8192] = X * W^T + bias, fused 2-bit dequant of W.
// Block 64m x 64n, 4 waves; each wave owns 64m x 16n.
// A: bf16 in LDS, 16 slabs of K=256, double-buffered, global_load_lds staging
//    (lane-linear LDS dest; XOR swizzle applied on the GLOBAL side).
// B: per-lane register dequant into MFMA fragments (no LDS), with the packed
//    ints + norms PREFETCHED one slab ahead (unconditional, clamped index) so
//    the scattered B loads are off the per-slab critical path.
template <bool XB>
__global__ __launch_bounds__(256, 2) void gemm2bit_kernel(
    const float*           __restrict__ xf,     // used when !XB
    const unsigned short*  __restrict__ xb,     // used when XB (bf16 x in ws)
    const int*             __restrict__ wq,     // int i holds weights 4i..4i+3 in bits 0,2,4,6
    const void*            __restrict__ wnorm,  // per-group-of-16 norm; fp32 or fp16, detected
    const float*           __restrict__ bias,
    float*                 __restrict__ out)
{
    __shared__ unsigned short ldsA[2][64 * SLAB];   // 2 x 32 KB

    const int t    = threadIdx.x;
    const int n0   = blockIdx.x * 64;
    const int m0   = blockIdx.y * 64;
    const int wave = t >> 6;
    const int lane = t & 63;
    const int l15  = lane & 15;
    const int quad = lane >> 4;

    // norm storage detection (valid norms in [1e-4, 0.0501]); grid-uniform.
    const float cand0 = *(const float*)wnorm;
    const bool  nf32  = (cand0 > 1e-5f && cand0 < 0.1f);
    const float*  nF = (const float*)wnorm;
    const __half* nH = (const __half*)wnorm;

    // this wave's output column / weight row
    const int   ncol = n0 + wave * 16 + l15;
    const float bv   = bias[ncol];
    const int*  wqW  = wq + ncol * (IN_F / 4) + quad * 2;  // + s*64 + ks*8
    const int   nrmW = ncol * (IN_F / 16) + (quad >> 1);   // + s*16 + ks*2

    // staging lane mapping: call c covers rows wave*16 + c*2 + (lane>>5),
    // stored chunk (lane&31); logical chunk = stored ^ (row&7).
    const int srl = lane >> 5;   // 0/1
    const int sj  = lane & 31;   // stored 8-short chunk within row

    // A fragment offsets (shorts): row=(i*16+l15), k-step ks ->
    //   off = row*SLAB + (ks>>1)*64 + (((ks&1)*4+quad)^(l15&7))*8
    const int swzE = ((quad      ) ^ (l15 & 7)) * 8;
    const int swzO = ((quad ^ 4  ) ^ (l15 & 7)) * 8;
    int fb[4];
#pragma unroll
    for (int i = 0; i < 4; ++i) fb[i] = (i * 16 + l15) * SLAB;

    float4v acc[4] = {};

    // ---- staging helper: slab s into buffer b ----
    auto stage = [&](int s, int b) {
        if constexpr (XB) {
#pragma unroll
            for (int c = 0; c < 8; ++c) {
                const int R  = wave * 16 + c * 2 + srl;          // block-local row
                const int lc = sj ^ (R & 7);                     // logical chunk
                const unsigned short* g = xb + (m0 + R) * IN_F + s * SLAB + lc * 8;
                gld_lds16(g, &ldsA[b][(wave * 16 + c * 2) * SLAB]);
            }
        } else {
#pragma unroll
            for (int c = 0; c < 8; ++c) {
                const int R  = wave * 16 + c * 2 + srl;
                const int lc = sj ^ (R & 7);
                const float4* g = (const float4*)(xf + (m0 + R) * IN_F + s * SLAB + lc * 8);
                float4 v0 = g[0], v1 = g[1];
                uint4 o;
                o.x = pack_bf16(v0.x, v0.y); o.y = pack_bf16(v0.z, v0.w);
                o.z = pack_bf16(v1.x, v1.y); o.w = pack_bf16(v1.z, v1.w);
                *(uint4*)&ldsA[b][(wave * 16 + c * 2) * SLAB + lane * 8] = o;
            }
        }
    };

    // ---- B prefetch helper: slab s -> qn/nn (unconditional, fully unrolled) ----
    auto load_b = [&](int s, int2 (&qn)[8], float (&nn)[8]) {
#pragma unroll
        for (int ks = 0; ks < 8; ++ks) {
            qn[ks] = *(const int2*)(wqW + s * 64 + ks * 8);
            const int gi = nrmW + s * 16 + ks * 2;
            nn[ks] = nf32 ? nF[gi] : __half2float(nH[gi]);
        }
    };

    // ---- prologue: stage slab 0, prefetch B for slab 0 ----
    stage(0, 0);
    int2  qn[8];
    float nn[8];
    load_b(0, qn, nn);

    for (int s = 0; s < NSLAB; ++s) {
        __syncthreads();   // drains vmcnt: slab-s DMA + slab-s B prefetch complete

        if (s + 1 < NSLAB) stage(s + 1, (s + 1) & 1);

        // consume this slab's B regs; immediately issue prefetch for next slab
        int2  qc[8];
        float nc[8];
#pragma unroll
        for (int ks = 0; ks < 8; ++ks) { qc[ks] = qn[ks]; nc[ks] = nn[ks]; }
        const int sl = (s + 1 < NSLAB) ? (s + 1) : s;   // clamped: always execute
        load_b(sl, qn, nn);

        const unsigned short* A = ldsA[s & 1];
#pragma unroll
        for (int ks = 0; ks < 8; ++ks) {
            const float nnv = nc[ks];
            const float sc  = nnv * (2.0f / 3.0f);
            const int qx = qc[ks].x, qy = qc[ks].y;

            float f0 = fmaf((float)((qx      ) & 3), sc, -nnv);
            float f1 = fmaf((float)((qx >>  2) & 3), sc, -nnv);
            float f2 = fmaf((float)((qx >>  4) & 3), sc, -nnv);
            float f3 = fmaf((float)((qx >>  6) & 3), sc, -nnv);
            float f4 = fmaf((float)((qy      ) & 3), sc, -nnv);
            float f5 = fmaf((float)((qy >>  2) & 3), sc, -nnv);
            float f6 = fmaf((float)((qy >>  4) & 3), sc, -nnv);
            float f7 = fmaf((float)((qy >>  6) & 3), sc, -nnv);

            BF8 bb;
            bb.u.x = pack_bf16(f0, f1);
            bb.u.y = pack_bf16(f2, f3);
            bb.u.z = pack_bf16(f4, f5);
            bb.u.w = pack_bf16(f6, f7);

            const int ko = (ks >> 1) * 64 + ((ks & 1) ? swzO : swzE);
#pragma unroll
            for (int i = 0; i < 4; ++i) {
                short8 a = *(const short8*)&A[fb[i] + ko];
                acc[i] = __builtin_amdgcn_mfma_f32_16x16x32_bf16(a, bb.s, acc[i], 0, 0, 0);
            }
        }
    }

    // ---- epilogue: D[row = m0 + i*16 + quad*4 + r][col = ncol] ----
#pragma unroll
    for (int i = 0; i < 4; ++i) {
        const int row0 = m0 + i * 16 + quad * 4;
#pragma unroll
        for (int r = 0; r < 4; ++r) {
            out[(row0 + r) * OUT_F + ncol] = acc[i][r] + bv;
        }
    }
}

extern "C" void kernel_launch(void* const* d_in, const int* in_sizes, int n_in,
                              void* d_out, int out_size, void* d_ws, size_t ws_size,
                              hipStream_t stream) {
    const float* x    = (const float*)d_in[0];
    const int*   wq   = (const int*)d_in[1];
    const void*  wn   = (const void*)d_in[2];
    const float* bias = (const float*)d_in[3];
    float*       out  = (float*)d_out;

    const bool use_ws = ws_size >= (size_t)(M_ROWS * IN_F * sizeof(unsigned short));

    dim3 grid(OUT_F / 64, M_ROWS / 64);  // 128 x 4 = 512 blocks (2 per CU)

    if (use_ws) {
        unsigned short* xb = (unsigned short*)d_ws;
        cvt_x_kernel<<<dim3((M_ROWS * IN_F / 4 + 255) / 256), 256, 0, stream>>>(x, xb);
        gemm2bit_kernel<true><<<grid, 256, 0, stream>>>(nullptr, xb, wq, wn, bias, out);
    } else {
        gemm2bit_kernel<false><<<grid, 256, 0, stream>>>(x, nullptr, wq, wn, bias, out);
    }
}

// Round 7
// 152.928 us; speedup vs baseline: 1.5684x; 1.0098x over previous
//
#include <hip/hip_runtime.h>
#include <hip/hip_bf16.h>
#include <hip/hip_fp16.h>

#define IN_F   4096
#define OUT_F  8192
#define M_ROWS 256
#define SLAB   128                 // k-elements per LDS slab (per K-group)
#define NSLAB  16                  // slabs per group; group K = 2048

typedef __attribute__((ext_vector_type(8))) short  short8;   // 8 bf16
typedef __attribute__((ext_vector_type(4))) float  float4v;  // 4 fp32 acc

union BF8 { uint4 u; short8 s; };

typedef __attribute__((address_space(1))) const unsigned int glb_uint;
typedef __attribute__((address_space(3))) unsigned int       lds_uint;

__device__ inline void gld_lds16(const void* g, void* l) {
    __builtin_amdgcn_global_load_lds((glb_uint*)g, (lds_uint*)l, 16, 0, 0);
}

// pack two fp32 into bf16x2 (truncation)
__device__ inline unsigned int pack_bf16(float lo, float hi) {
    return __builtin_amdgcn_perm(__float_as_uint(hi), __float_as_uint(lo), 0x07060302u);
}

// x fp32 -> bf16 (truncated) into workspace
__global__ void cvt_x_kernel(const float* __restrict__ x, unsigned short* __restrict__ xb) {
    int i = blockIdx.x * blockDim.x + threadIdx.x;   // one float4 per thread
    if (i < (M_ROWS * IN_F) / 4) {
        float4 v = ((const float4*)x)[i];
        uint2 o;
        o.x = pack_bf16(v.x, v.y);
        o.y = pack_bf16(v.z, v.w);
        ((uint2*)xb)[i] = o;
    }
}

// C[256,8192] = X * W^T + bias, fused 2-bit dequant of W.
// Block 64m x 64n, 512 threads = 8 waves, IN-BLOCK K-SPLIT:
//   waves 0-3 -> K [0,2048), waves 4-7 -> K [2048,4096), lockstep slabs.
// A: bf16 in LDS per group, 16 slabs of 128 k, double-buffered, global_load_lds
//    staging (lane-linear dest; XOR swizzle applied on the GLOBAL side).
// B: per-lane register dequant into MFMA fragments (no LDS), prefetched 1 slab.
// Epilogue: group-1 partials through LDS, group-0 adds + bias + store.
template <bool XB>
__global__ __launch_bounds__(512, 4) void gemm2bit_kernel(
    const float*           __restrict__ xf,     // used when !XB
    const unsigned short*  __restrict__ xb,     // used when XB (bf16 x in ws)
    const int*             __restrict__ wq,     // int i holds weights 4i..4i+3 in bits 0,2,4,6
    const void*            __restrict__ wnorm,  // per-group-of-16 norm; fp32 or fp16, detected
    const float*           __restrict__ bias,
    float*                 __restrict__ out)
{
    __shared__ unsigned short ldsA[2][2][64 * SLAB];   // [kgroup][buf] = 4 x 16 KB

    const int t    = threadIdx.x;
    const int n0   = blockIdx.x * 64;
    const int m0   = blockIdx.y * 64;
    const int wave = t >> 6;         // 0..7
    const int lane = t & 63;
    const int gw   = wave & 3;       // wave index within K-group
    const int grp  = wave >> 2;      // K-group 0/1
    const int l15  = lane & 15;
    const int quad = lane >> 4;

    // norm storage detection (valid norms in [1e-4, 0.0501]); grid-uniform.
    const float cand0 = *(const float*)wnorm;
    const bool  nf32  = (cand0 > 1e-5f && cand0 < 0.1f);
    const float*  nF = (const float*)wnorm;
    const __half* nH = (const __half*)wnorm;

    // this wave's output column / weight row, and K-group base
    const int   ncol = n0 + gw * 16 + l15;
    const float bv   = bias[ncol];
    const int   kgrp = grp * (IN_F / 2);                         // 0 or 2048

    const int* wqW  = wq + ncol * (IN_F / 4) + (kgrp >> 2) + quad * 2;  // + s*32 + ks*8
    const int  nrmW = ncol * (IN_F / 16) + (kgrp >> 4) + (quad >> 1);   // + s*8  + ks*2

    // staging lane mapping: call c covers rows gw*16 + c*4 + (lane>>4),
    // stored chunk (lane&15); logical chunk = stored ^ (row&7) within 8-chunk halves.
    const int srow4 = lane >> 4;   // 0..3
    const int sj    = lane & 15;   // stored 8-short chunk within row

    // A fragment offsets (shorts): row=(i*16+l15); k-step ks -> chunk c=ks*4+quad,
    // stored = (c&8) | ((c ^ (l15&7)) & 7)
    int stv[4];
#pragma unroll
    for (int ks = 0; ks < 4; ++ks) {
        const int c = ks * 4 + quad;
        stv[ks] = ((c & 8) | ((c ^ (l15 & 7)) & 7)) * 8;
    }
    int fb[4];
#pragma unroll
    for (int i = 0; i < 4; ++i) fb[i] = (i * 16 + l15) * SLAB;

    float4v acc[4] = {};

    // ---- staging helper: group slab s into buffer b (16 KB per group) ----
    auto stage = [&](int s, int b) {
        const int kbase = kgrp + s * SLAB;
        if constexpr (XB) {
#pragma unroll
            for (int c = 0; c < 4; ++c) {
                const int R  = gw * 16 + c * 4 + srow4;               // block-local row
                const int lc = (sj & 8) | ((sj ^ (R & 7)) & 7);       // logical chunk
                const unsigned short* g = xb + (m0 + R) * IN_F + kbase + lc * 8;
                gld_lds16(g, &ldsA[grp][b][(gw * 16 + c * 4) * SLAB]);
            }
        } else {
#pragma unroll
            for (int c = 0; c < 4; ++c) {
                const int R  = gw * 16 + c * 4 + srow4;
                const int lc = (sj & 8) | ((sj ^ (R & 7)) & 7);
                const float4* g = (const float4*)(xf + (m0 + R) * IN_F + kbase + lc * 8);
                float4 v0 = g[0], v1 = g[1];
                uint4 o;
                o.x = pack_bf16(v0.x, v0.y); o.y = pack_bf16(v0.z, v0.w);
                o.z = pack_bf16(v1.x, v1.y); o.w = pack_bf16(v1.z, v1.w);
                *(uint4*)&ldsA[grp][b][R * SLAB + sj * 8] = o;
            }
        }
    };

    // ---- B loads for one slab (4 k-steps) ----
    auto load_b = [&](int s, int2 (&q)[4], float (&n)[4]) {
#pragma unroll
        for (int ks = 0; ks < 4; ++ks) {
            q[ks] = *(const int2*)(wqW + s * 32 + ks * 8);
            const int gi = nrmW + s * 8 + ks * 2;
            n[ks] = nf32 ? nF[gi] : __half2float(nH[gi]);
        }
    };

    // ---- prologue ----
    stage(0, 0);
    int2  qn[4];
    float nn[4];
    load_b(0, qn, nn);

    for (int s = 0; s < NSLAB; ++s) {
        __syncthreads();   // slab-s DMA drained for both groups

        if (s + 1 < NSLAB) stage(s + 1, (s + 1) & 1);

        int2  qc[4];
        float nc[4];
#pragma unroll
        for (int ks = 0; ks < 4; ++ks) { qc[ks] = qn[ks]; nc[ks] = nn[ks]; }
        const int sl = (s + 1 < NSLAB) ? (s + 1) : s;   // clamped: unconditional
        load_b(sl, qn, nn);

        const unsigned short* A = ldsA[grp][s & 1];
#pragma unroll
        for (int ks = 0; ks < 4; ++ks) {
            const float nnv = nc[ks];
            const float sc  = nnv * (2.0f / 3.0f);
            const int qx = qc[ks].x, qy = qc[ks].y;

            float f0 = fmaf((float)((qx      ) & 3), sc, -nnv);
            float f1 = fmaf((float)((qx >>  2) & 3), sc, -nnv);
            float f2 = fmaf((float)((qx >>  4) & 3), sc, -nnv);
            float f3 = fmaf((float)((qx >>  6) & 3), sc, -nnv);
            float f4 = fmaf((float)((qy      ) & 3), sc, -nnv);
            float f5 = fmaf((float)((qy >>  2) & 3), sc, -nnv);
            float f6 = fmaf((float)((qy >>  4) & 3), sc, -nnv);
            float f7 = fmaf((float)((qy >>  6) & 3), sc, -nnv);

            BF8 bb;
            bb.u.x = pack_bf16(f0, f1);
            bb.u.y = pack_bf16(f2, f3);
            bb.u.z = pack_bf16(f4, f5);
            bb.u.w = pack_bf16(f6, f7);

#pragma unroll
            for (int i = 0; i < 4; ++i) {
                short8 a = *(const short8*)&A[fb[i] + stv[ks]];
                acc[i] = __builtin_amdgcn_mfma_f32_16x16x32_bf16(a, bb.s, acc[i], 0, 0, 0);
            }
        }
    }

    // ---- cross-group reduction (reuse ldsA as 16 KB float buffer) ----
    __syncthreads();                      // all LDS compute reads complete
    float* red = (float*)&ldsA[0][0][0];  // 256 lanes x 16 f32 = 16 KB
    if (grp == 1) {
#pragma unroll
        for (int i = 0; i < 4; ++i)
            *(float4*)&red[(gw * 64 + lane) * 16 + i * 4] = *(float4*)&acc[i];
    }
    __syncthreads();
    if (grp == 0) {
#pragma unroll
        for (int i = 0; i < 4; ++i) {
            const float4 o = *(const float4*)&red[(gw * 64 + lane) * 16 + i * 4];
            const int row0 = m0 + i * 16 + quad * 4;
            out[(row0 + 0) * OUT_F + ncol] = acc[i][0] + o.x + bv;
            out[(row0 + 1) * OUT_F + ncol] = acc[i][1] + o.y + bv;
            out[(row0 + 2) * OUT_F + ncol] = acc[i][2] + o.z + bv;
            out[(row0 + 3) * OUT_F + ncol] = acc[i][3] + o.w + bv;
        }
    }
}

extern "C" void kernel_launch(void* const* d_in, const int* in_sizes, int n_in,
                              void* d_out, int out_size, void* d_ws, size_t ws_size,
                              hipStream_t stream) {
    const float* x    = (const float*)d_in[0];
    const int*   wq   = (const int*)d_in[1];
    const void*  wn   = (const void*)d_in[2];
    const float* bias = (const float*)d_in[3];
    float*       out  = (float*)d_out;

    const bool use_ws = ws_size >= (size_t)(M_ROWS * IN_F * sizeof(unsigned short));

    dim3 grid(OUT_F / 64, M_ROWS / 64);  // 128 x 4 = 512 blocks, 8 waves each
                                         // -> 4096 waves = 16 waves/CU

    if (use_ws) {
        unsigned short* xb = (unsigned short*)d_ws;
        cvt_x_kernel<<<dim3((M_ROWS * IN_F / 4 + 255) / 256), 256, 0, stream>>>(x, xb);
        gemm2bit_kernel<true><<<grid, 512, 0, stream>>>(nullptr, xb, wq, wn, bias, out);
    } else {
        gemm2bit_kernel<false><<<grid, 512, 0, stream>>>(x, nullptr, wq, wn, bias, out);
    }
}

// Round 8
// 130.066 us; speedup vs baseline: 1.8441x; 1.1758x over previous
//
#include <hip/hip_runtime.h>
#include <hip/hip_bf16.h>
#include <hip/hip_fp16.h>

#define IN_F   4096
#define OUT_F  8192
#define M_ROWS 256

typedef __attribute__((ext_vector_type(8)))  short short8;    // 8 bf16
typedef __attribute__((ext_vector_type(4)))  float float4v;   // 4 fp32
typedef __attribute__((ext_vector_type(16))) float float16v;  // 16 fp32 acc (32x32)

union BF8 { uint4 u; short8 s; };

typedef __attribute__((address_space(1))) const unsigned int glb_uint;
typedef __attribute__((address_space(3))) unsigned int       lds_uint;

__device__ inline void gld_lds16(const void* g, void* l) {
    __builtin_amdgcn_global_load_lds((glb_uint*)g, (lds_uint*)l, 16, 0, 0);
}

__device__ inline unsigned int pack_bf16(float lo, float hi) {
    return __builtin_amdgcn_perm(__float_as_uint(hi), __float_as_uint(lo), 0x07060302u);
}

// ---------------- prep kernels ----------------

// x fp32 -> bf16 into ws
__global__ void cvt_x_kernel(const float* __restrict__ x, unsigned short* __restrict__ xb) {
    int i = blockIdx.x * blockDim.x + threadIdx.x;
    if (i < (M_ROWS * IN_F) / 4) {
        float4 v = ((const float4*)x)[i];
        uint2 o;
        o.x = pack_bf16(v.x, v.y);
        o.y = pack_bf16(v.z, v.w);
        ((uint2*)xb)[i] = o;
    }
}

// wqT[kq][n] = wq[n][kq]   (kq in [0,1024), n in [0,8192))
__global__ __launch_bounds__(256) void transpose_wq_kernel(
    const int* __restrict__ wq, int* __restrict__ wqT) {
    __shared__ int tile[64][65];
    const int t   = threadIdx.x;
    const int kq0 = blockIdx.x * 64;
    const int n0  = blockIdx.y * 64;
    {
        const int r  = t >> 4;          // 0..15
        const int c4 = (t & 15) * 4;    // 0..60
#pragma unroll
        for (int it = 0; it < 4; ++it) {
            const int rr = it * 16 + r;
            const int4 v = *(const int4*)(wq + (n0 + rr) * (IN_F / 4) + kq0 + c4);
            tile[rr][c4 + 0] = v.x; tile[rr][c4 + 1] = v.y;
            tile[rr][c4 + 2] = v.z; tile[rr][c4 + 3] = v.w;
        }
    }
    __syncthreads();
    {
        const int kr = t >> 6;          // 0..3
        const int nc = t & 63;
#pragma unroll
        for (int it = 0; it < 16; ++it) {
            const int kk = it * 4 + kr;
            wqT[(kq0 + kk) * OUT_F + n0 + nc] = tile[nc][kk];
        }
    }
}

// nT[kg][n] = norm[n][kg] as fp32  (kg in [0,256)); source fp32 or fp16, detected
__global__ __launch_bounds__(256) void transpose_nrm_kernel(
    const void* __restrict__ nrm, float* __restrict__ nT) {
    __shared__ float tile[64][65];
    const float cand0 = *(const float*)nrm;
    const bool  nf32  = (cand0 > 1e-5f && cand0 < 0.1f);
    const float*  nF = (const float*)nrm;
    const __half* nH = (const __half*)nrm;
    const int t   = threadIdx.x;
    const int kg0 = blockIdx.x * 64;
    const int n0  = blockIdx.y * 64;
#pragma unroll
    for (int it = 0; it < 16; ++it) {
        const int idx = it * 256 + t;
        const int r = idx >> 6, c = idx & 63;
        const int gi = (n0 + r) * (IN_F / 16) + kg0 + c;
        tile[r][c] = nf32 ? nF[gi] : __half2float(nH[gi]);
    }
    __syncthreads();
#pragma unroll
    for (int it = 0; it < 16; ++it) {
        const int idx = it * 256 + t;
        const int kr = idx >> 6, nc = idx & 63;
        nT[(kg0 + kr) * OUT_F + n0 + nc] = tile[nc][kr];
    }
}

// ---------------- main GEMM (transposed-B path) ----------------
// Block 64m x 64n, 512 threads = 8 waves = 2 n-waves x 4 k-groups (K=1024 each).
// MFMA 32x32x16. Wave-tile 64m x 32n (2 acc tiles). A via LDS (DMA, swizzled,
// 16 slabs of 64k per k-group, double-buffered). B: coalesced loads from
// transposed wqT/nT, per-lane dequant into fragments. In-LDS k-reduction.
__global__ __launch_bounds__(512, 4) void gemm2bit_t_kernel(
    const unsigned short* __restrict__ xb,
    const int*            __restrict__ wqT,   // [1024][8192]
    const float*          __restrict__ nT,    // [256][8192]
    const float*          __restrict__ bias,
    float*                __restrict__ out)
{
    __shared__ unsigned short smA[4][2][64 * 64];   // 64 KB; reused for reduction

    const int t    = threadIdx.x;
    const int wave = t >> 6;
    const int lane = t & 63;
    const int nw   = wave & 1;       // n-wave 0/1
    const int kg   = wave >> 1;      // k-group 0..3
    const int n0   = blockIdx.x * 64;
    const int m0   = blockIdx.y * 64;
    const int l31  = lane & 31;
    const int kh   = lane >> 5;      // k-half 0/1

    const int   ncol = n0 + nw * 32 + l31;
    const float bv   = bias[ncol];
    const int   kbase = kg * 1024;

    // B pointers (coalesced over l31): k16-step g16 (local to k-group):
    //   qA = wqT[((kbase>>2) + g16*4 + kh*2)][ncol], qB = next kq row
    //   nv = nT[((kbase>>4) + g16)][ncol]
    const int*   qptr = wqT + ((kbase >> 2) + kh * 2) * OUT_F + ncol;
    const float* nptr = nT  + (kbase >> 4) * OUT_F + ncol;

    // A staging (DMA): wave covers rows nw*32 + c*8 + (lane>>3), chunk lane&7
    const int srow = nw * 32 + (lane >> 3);
    const int schk = lane & 7;
    const unsigned short* gA =
        xb + (m0 + srow) * IN_F + kbase + ((schk ^ (srow & 7)) << 3);

    // A fragment read offsets: a_i at row (i*32 + l31), chunk (w*2+kh)^(l31&7)
    const int fswz  = l31 & 7;
    const int frow0 = l31 * 64;
    const int frow1 = (32 + l31) * 64;

    float16v acc0 = {}, acc1 = {};

    auto stage = [&](int s, int b) {
        unsigned short* dst = &smA[kg][b][(nw * 32) * 64];
        const unsigned short* src = gA + s * 64;
#pragma unroll
        for (int c = 0; c < 4; ++c)
            gld_lds16(src + c * 8 * IN_F, dst + c * 8 * 64);
    };

    int qA[4], qB[4]; float nv[4];
    auto load_b = [&](int s) {
#pragma unroll
        for (int w = 0; w < 4; ++w) {
            const int g16 = s * 4 + w;
            qA[w] = qptr[(g16 * 4) * OUT_F];
            qB[w] = qptr[(g16 * 4 + 1) * OUT_F];
            nv[w] = nptr[g16 * OUT_F];
        }
    };

    stage(0, 0);
    load_b(0);

    for (int s = 0; s < 16; ++s) {
        __syncthreads();   // slab-s DMA drained (block-wide)

        if (s + 1 < 16) stage(s + 1, (s + 1) & 1);

        int qAc[4], qBc[4]; float nvc[4];
#pragma unroll
        for (int w = 0; w < 4; ++w) { qAc[w] = qA[w]; qBc[w] = qB[w]; nvc[w] = nv[w]; }
        load_b((s + 1 < 16) ? s + 1 : s);   // unconditional (clamped) -> no spill path

        const unsigned short* A = smA[kg][s & 1];
#pragma unroll
        for (int w = 0; w < 4; ++w) {
            const float nn = nvc[w];
            const float sc = nn * (2.0f / 3.0f);
            const int qx = qAc[w], qy = qBc[w];

            float f0 = fmaf((float)((qx      ) & 3), sc, -nn);
            float f1 = fmaf((float)((qx >>  2) & 3), sc, -nn);
            float f2 = fmaf((float)((qx >>  4) & 3), sc, -nn);
            float f3 = fmaf((float)((qx >>  6) & 3), sc, -nn);
            float f4 = fmaf((float)((qy      ) & 3), sc, -nn);
            float f5 = fmaf((float)((qy >>  2) & 3), sc, -nn);
            float f6 = fmaf((float)((qy >>  4) & 3), sc, -nn);
            float f7 = fmaf((float)((qy >>  6) & 3), sc, -nn);

            BF8 bb;
            bb.u.x = pack_bf16(f0, f1);
            bb.u.y = pack_bf16(f2, f3);
            bb.u.z = pack_bf16(f4, f5);
            bb.u.w = pack_bf16(f6, f7);

            const int co = ((w * 2 + kh) ^ fswz) << 3;
            short8 a0 = *(const short8*)&A[frow0 + co];
            acc0 = __builtin_amdgcn_mfma_f32_32x32x16_bf16(a0, bb.s, acc0, 0, 0, 0);
            short8 a1 = *(const short8*)&A[frow1 + co];
            acc1 = __builtin_amdgcn_mfma_f32_32x32x16_bf16(a1, bb.s, acc1, 0, 0, 0);
        }
    }

    // ---- in-LDS reduction over 4 k-groups, then store by kg==0 waves ----
    __syncthreads();
    float4* red = (float4*)&smA[0][0][0];   // [j4][512 lanes]: idx = j4*512 + wave*64+lane
    if (kg != 0) {
        const int base = wave * 64 + lane;
#pragma unroll
        for (int j4 = 0; j4 < 4; ++j4) {
            float4 v0 = { acc0[j4*4+0], acc0[j4*4+1], acc0[j4*4+2], acc0[j4*4+3] };
            float4 v1 = { acc1[j4*4+0], acc1[j4*4+1], acc1[j4*4+2], acc1[j4*4+3] };
            red[(j4    ) * 512 + base] = v0;
            red[(j4 + 4) * 512 + base] = v1;
        }
    }
    __syncthreads();
    if (kg == 0) {
#pragma unroll
        for (int p = 1; p < 4; ++p) {
            const int base = (p * 2 + nw) * 64 + lane;
#pragma unroll
            for (int j4 = 0; j4 < 4; ++j4) {
                const float4 v0 = red[(j4    ) * 512 + base];
                const float4 v1 = red[(j4 + 4) * 512 + base];
                acc0[j4*4+0] += v0.x; acc0[j4*4+1] += v0.y; acc0[j4*4+2] += v0.z; acc0[j4*4+3] += v0.w;
                acc1[j4*4+0] += v1.x; acc1[j4*4+1] += v1.y; acc1[j4*4+2] += v1.z; acc1[j4*4+3] += v1.w;
            }
        }
#pragma unroll
        for (int r = 0; r < 16; ++r) {
            const int row = (r & 3) + 8 * (r >> 2) + 4 * kh;   // verified 32x32 C/D map
            out[(m0 + row) * OUT_F + ncol]      = acc0[r] + bv;
            out[(m0 + 32 + row) * OUT_F + ncol] = acc1[r] + bv;
        }
    }
}

// ---------------- fallback (round-7 verified kernel) ----------------
#define SLAB   128
#define NSLAB  16
template <bool XB>
__global__ __launch_bounds__(512, 4) void gemm2bit_kernel(
    const float*           __restrict__ xf,
    const unsigned short*  __restrict__ xb,
    const int*             __restrict__ wq,
    const void*            __restrict__ wnorm,
    const float*           __restrict__ bias,
    float*                 __restrict__ out)
{
    __shared__ unsigned short ldsA[2][2][64 * SLAB];
    const int t    = threadIdx.x;
    const int n0   = blockIdx.x * 64;
    const int m0   = blockIdx.y * 64;
    const int wave = t >> 6;
    const int lane = t & 63;
    const int gw   = wave & 3;
    const int grp  = wave >> 2;
    const int l15  = lane & 15;
    const int quad = lane >> 4;
    const float cand0 = *(const float*)wnorm;
    const bool  nf32  = (cand0 > 1e-5f && cand0 < 0.1f);
    const float*  nF = (const float*)wnorm;
    const __half* nH = (const __half*)wnorm;
    const int   ncol = n0 + gw * 16 + l15;
    const float bv   = bias[ncol];
    const int   kgrp = grp * (IN_F / 2);
    const int* wqW  = wq + ncol * (IN_F / 4) + (kgrp >> 2) + quad * 2;
    const int  nrmW = ncol * (IN_F / 16) + (kgrp >> 4) + (quad >> 1);
    const int srow4 = lane >> 4;
    const int sj    = lane & 15;
    int stv[4];
#pragma unroll
    for (int ks = 0; ks < 4; ++ks) {
        const int c = ks * 4 + quad;
        stv[ks] = ((c & 8) | ((c ^ (l15 & 7)) & 7)) * 8;
    }
    int fb[4];
#pragma unroll
    for (int i = 0; i < 4; ++i) fb[i] = (i * 16 + l15) * SLAB;
    float4v acc[4] = {};
    auto stage = [&](int s, int b) {
        const int kbase = kgrp + s * SLAB;
        if constexpr (XB) {
#pragma unroll
            for (int c = 0; c < 4; ++c) {
                const int R  = gw * 16 + c * 4 + srow4;
                const int lc = (sj & 8) | ((sj ^ (R & 7)) & 7);
                const unsigned short* g = xb + (m0 + R) * IN_F + kbase + lc * 8;
                gld_lds16(g, &ldsA[grp][b][(gw * 16 + c * 4) * SLAB]);
            }
        } else {
#pragma unroll
            for (int c = 0; c < 4; ++c) {
                const int R  = gw * 16 + c * 4 + srow4;
                const int lc = (sj & 8) | ((sj ^ (R & 7)) & 7);
                const float4* g = (const float4*)(xf + (m0 + R) * IN_F + kbase + lc * 8);
                float4 v0 = g[0], v1 = g[1];
                uint4 o;
                o.x = pack_bf16(v0.x, v0.y); o.y = pack_bf16(v0.z, v0.w);
                o.z = pack_bf16(v1.x, v1.y); o.w = pack_bf16(v1.z, v1.w);
                *(uint4*)&ldsA[grp][b][R * SLAB + sj * 8] = o;
            }
        }
    };
    auto load_b = [&](int s, int2 (&q)[4], float (&n)[4]) {
#pragma unroll
        for (int ks = 0; ks < 4; ++ks) {
            q[ks] = *(const int2*)(wqW + s * 32 + ks * 8);
            const int gi = nrmW + s * 8 + ks * 2;
            n[ks] = nf32 ? nF[gi] : __half2float(nH[gi]);
        }
    };
    stage(0, 0);
    int2 qn[4]; float nn[4];
    load_b(0, qn, nn);
    for (int s = 0; s < NSLAB; ++s) {
        __syncthreads();
        if (s + 1 < NSLAB) stage(s + 1, (s + 1) & 1);
        int2 qc[4]; float nc[4];
#pragma unroll
        for (int ks = 0; ks < 4; ++ks) { qc[ks] = qn[ks]; nc[ks] = nn[ks]; }
        const int sl = (s + 1 < NSLAB) ? (s + 1) : s;
        load_b(sl, qn, nn);
        const unsigned short* A = ldsA[grp][s & 1];
#pragma unroll
        for (int ks = 0; ks < 4; ++ks) {
            const float nnv = nc[ks];
            const float sc  = nnv * (2.0f / 3.0f);
            const int qx = qc[ks].x, qy = qc[ks].y;
            float f0 = fmaf((float)((qx      ) & 3), sc, -nnv);
            float f1 = fmaf((float)((qx >>  2) & 3), sc, -nnv);
            float f2 = fmaf((float)((qx >>  4) & 3), sc, -nnv);
            float f3 = fmaf((float)((qx >>  6) & 3), sc, -nnv);
            float f4 = fmaf((float)((qy      ) & 3), sc, -nnv);
            float f5 = fmaf((float)((qy >>  2) & 3), sc, -nnv);
            float f6 = fmaf((float)((qy >>  4) & 3), sc, -nnv);
            float f7 = fmaf((float)((qy >>  6) & 3), sc, -nnv);
            BF8 bb;
            bb.u.x = pack_bf16(f0, f1);
            bb.u.y = pack_bf16(f2, f3);
            bb.u.z = pack_bf16(f4, f5);
            bb.u.w = pack_bf16(f6, f7);
#pragma unroll
            for (int i = 0; i < 4; ++i) {
                short8 a = *(const short8*)&A[fb[i] + stv[ks]];
                acc[i] = __builtin_amdgcn_mfma_f32_16x16x32_bf16(a, bb.s, acc[i], 0, 0, 0);
            }
        }
    }
    __syncthreads();
    float* red = (float*)&ldsA[0][0][0];
    if (grp == 1) {
#pragma unroll
        for (int i = 0; i < 4; ++i)
            *(float4*)&red[(gw * 64 + lane) * 16 + i * 4] = *(float4*)&acc[i];
    }
    __syncthreads();
    if (grp == 0) {
#pragma unroll
        for (int i = 0; i < 4; ++i) {
            const float4 o = *(const float4*)&red[(gw * 64 + lane) * 16 + i * 4];
            const int row0 = m0 + i * 16 + quad * 4;
            out[(row0 + 0) * OUT_F + ncol] = acc[i][0] + o.x + bv;
            out[(row0 + 1) * OUT_F + ncol] = acc[i][1] + o.y + bv;
            out[(row0 + 2) * OUT_F + ncol] = acc[i][2] + o.z + bv;
            out[(row0 + 3) * OUT_F + ncol] = acc[i][3] + o.w + bv;
        }
    }
}

extern "C" void kernel_launch(void* const* d_in, const int* in_sizes, int n_in,
                              void* d_out, int out_size, void* d_ws, size_t ws_size,
                              hipStream_t stream) {
    const float* x    = (const float*)d_in[0];
    const int*   wq   = (const int*)d_in[1];
    const void*  wn   = (const void*)d_in[2];
    const float* bias = (const float*)d_in[3];
    float*       out  = (float*)d_out;

    const size_t XB_BYTES  = (size_t)M_ROWS * IN_F * 2;               // 2 MB
    const size_t WQT_BYTES = (size_t)(IN_F / 4) * OUT_F * 4;          // 32 MB
    const size_t NT_BYTES  = (size_t)(IN_F / 16) * OUT_F * 4;         // 8 MB
    const size_t FULL_WS   = XB_BYTES + WQT_BYTES + NT_BYTES;         // 44,040,192

    dim3 grid64(OUT_F / 64, M_ROWS / 64);   // 128 x 4

    if (ws_size >= FULL_WS) {
        unsigned short* xb  = (unsigned short*)d_ws;
        int*            wqT = (int*)  ((char*)d_ws + XB_BYTES);
        float*          nTp = (float*)((char*)d_ws + XB_BYTES + WQT_BYTES);
        cvt_x_kernel<<<dim3((M_ROWS * IN_F / 4 + 255) / 256), 256, 0, stream>>>(x, xb);
        transpose_wq_kernel<<<dim3((IN_F / 4) / 64, OUT_F / 64), 256, 0, stream>>>(wq, wqT);
        transpose_nrm_kernel<<<dim3((IN_F / 16) / 64, OUT_F / 64), 256, 0, stream>>>(wn, nTp);
        gemm2bit_t_kernel<<<grid64, 512, 0, stream>>>(xb, wqT, nTp, bias, out);
    } else if (ws_size >= XB_BYTES) {
        unsigned short* xb = (unsigned short*)d_ws;
        cvt_x_kernel<<<dim3((M_ROWS * IN_F / 4 + 255) / 256), 256, 0, stream>>>(x, xb);
        gemm2bit_kernel<true><<<grid64, 512, 0, stream>>>(nullptr, xb, wq, wn, bias, out);
    } else {
        gemm2bit_kernel<false><<<grid64, 512, 0, stream>>>(x, nullptr, wq, wn, bias, out);
    }
}